// Round 7
// baseline (49.863 us; speedup 1.0000x reference)
//
#include <hip/hip_runtime.h>

#define TDIM 4096
#define SBAR() __builtin_amdgcn_sched_barrier(0)

// frame layout: f[0..8]=R (row major), f[9..11]=pos, f[12..15]=parent raw quat
__device__ __forceinline__ void fk_step(float* __restrict__ f,
                                        const float* __restrict__ q,
                                        float o0, float o1, float o2) {
  const float pw = f[12], px = f[13], py = f[14], pz = f[15];
  // loc = conj(parent_q) * q
  float lw = pw*q[0] + px*q[1] + py*q[2] + pz*q[3];
  float lx = pw*q[1] - px*q[0] - py*q[3] + pz*q[2];
  float ly = pw*q[2] + px*q[3] - py*q[0] - pz*q[1];
  float lz = pw*q[3] - px*q[2] + py*q[1] - pz*q[0];
  float n2 = lw*lw + lx*lx + ly*ly + lz*lz;
  float inv = rsqrtf(fmaxf(n2, 1e-16f));
  lw *= inv; lx *= inv; ly *= inv; lz *= inv;
  float xx = lx*lx, yy = ly*ly, zz = lz*lz;
  float xy = lx*ly, xz = lx*lz, yz = ly*lz;
  float wx = lw*lx, wy = lw*ly, wz = lw*lz;
  float m0 = 1.0f-2.0f*(yy+zz), m1 = 2.0f*(xy-wz),      m2 = 2.0f*(xz+wy);
  float m3 = 2.0f*(xy+wz),      m4 = 1.0f-2.0f*(xx+zz), m5 = 2.0f*(yz-wx);
  float m6 = 2.0f*(xz-wy),      m7 = 2.0f*(yz+wx),      m8 = 1.0f-2.0f*(xx+yy);
  f[9]  += f[0]*o0 + f[1]*o1 + f[2]*o2;
  f[10] += f[3]*o0 + f[4]*o1 + f[5]*o2;
  f[11] += f[6]*o0 + f[7]*o1 + f[8]*o2;
  float r0 = f[0]*m0 + f[1]*m3 + f[2]*m6;
  float r1 = f[0]*m1 + f[1]*m4 + f[2]*m7;
  float r2 = f[0]*m2 + f[1]*m5 + f[2]*m8;
  float r3 = f[3]*m0 + f[4]*m3 + f[5]*m6;
  float r4 = f[3]*m1 + f[4]*m4 + f[5]*m7;
  float r5 = f[3]*m2 + f[4]*m5 + f[5]*m8;
  float r6 = f[6]*m0 + f[7]*m3 + f[8]*m6;
  float r7 = f[6]*m1 + f[7]*m4 + f[8]*m7;
  float r8 = f[6]*m2 + f[7]*m5 + f[8]*m8;
  f[0]=r0; f[1]=r1; f[2]=r2; f[3]=r3; f[4]=r4; f[5]=r5; f[6]=r6; f[7]=r7; f[8]=r8;
  f[12]=q[0]; f[13]=q[1]; f[14]=q[2]; f[15]=q[3];
}

// block = 768 threads: waves 0-3 = ik, 4-7 = dec, 8-11 = tgt, each covering the
// same 256 (b,t) pairs. Coupling via LDS exchange once per joint.
__global__ __launch_bounds__(768, 4) void fk_loss_kernel(
    const float* __restrict__ ik,   // (32, 168, 4096)
    const float* __restrict__ dec,  // (32, 176, 4096)
    const float* __restrict__ tgt,  // (32, 176, 4096)
    const float* __restrict__ mean, // (176,)
    const float* __restrict__ stdv, // (176,)
    const float* __restrict__ offs, // (22, 3)
    float* __restrict__ out)
{
  __shared__ float s_mean[176];
  __shared__ float s_std[176];
  __shared__ float xbuf[2][12][256];   // [parity][component][inner] — conflict-free
  __shared__ float s_wsum[12];
  const int tid = threadIdx.x;
  for (int i = tid; i < 176; i += 768) { s_mean[i] = mean[i]; s_std[i] = stdv[i]; }
  __syncthreads();

  const int role  = tid >> 8;          // 0=ik, 1=dec, 2=tgt (wave-aligned)
  const int inner = tid & 255;
  const int idx = blockIdx.x * 256 + inner;   // 0 .. 131071
  const int b = idx >> 12;
  const int t = idx & 4095;

  // pre-shift ik pointer by -8 channels so all roles index channel j*8+c
  const float* __restrict__ p =
      (role == 0) ? (ik  + ((size_t)b * 168) * TDIM + t - 8 * TDIM)
    : (role == 1) ? (dec + ((size_t)b * 176) * TDIM + t)
    :               (tgt + ((size_t)b * 176) * TDIM + t);

  float see_p = 0.f, see_m = 0.f, srg_p = 0.f, srg_m = 0.f;
  float f[16], sv[16], pq[4];
  float S0[4], S1[4];

  // root parent quat: identity for ik/dec (set_root=True), denormed tgt ch 0..3 for tgt
  pq[0] = 1.f; pq[1] = 0.f; pq[2] = 0.f; pq[3] = 0.f;
  if (role == 2) {
    #pragma unroll
    for (int c = 0; c < 4; c++) pq[c] = fmaf(p[c * TDIM], s_std[c], s_mean[c]);
  }

#define LOADJ(buf, j)                                                          \
  { _Pragma("unroll")                                                          \
    for (int c = 0; c < 4; c++) buf[c] = p[((j)*8 + c) * TDIM]; }

#define COMP(buf, j)                                                           \
  { float q[4];                                                                \
    _Pragma("unroll")                                                          \
    for (int c = 0; c < 4; c++)                                                \
      q[c] = fmaf(buf[c], s_std[(j)*8 + c], s_mean[(j)*8 + c]);                \
    fk_step(f, q, offs[(j)*3], offs[(j)*3 + 1], offs[(j)*3 + 2]); }

// exchange + diff at joint j. Writer: tgt if EE else dec. Reader: ik.
// __syncthreads is in uniform control flow. Double-buffer parity j&1 makes
// one barrier per joint race-free (write j+2 ordered after barrier j+1 > read j).
#define XCHG(j, IS_EE)                                                         \
  { if (role == ((IS_EE) ? 2 : 1)) {                                           \
      _Pragma("unroll")                                                        \
      for (int c = 0; c < 12; c++) xbuf[(j)&1][c][inner] = f[c];               \
    }                                                                          \
    __syncthreads();                                                           \
    if (role == 0) {                                                           \
      if (IS_EE) {                                                             \
        _Pragma("unroll")                                                      \
        for (int c = 0; c < 3; c++) { float d = f[9+c] - xbuf[(j)&1][9+c][inner]; see_p = fmaf(d, d, see_p); } \
        _Pragma("unroll")                                                      \
        for (int c = 0; c < 9; c++) { float d = f[c]   - xbuf[(j)&1][c][inner];   see_m = fmaf(d, d, see_m); } \
      } else {                                                                 \
        _Pragma("unroll")                                                      \
        for (int c = 0; c < 3; c++) { float d = xbuf[(j)&1][9+c][inner] - f[9+c]; srg_p = fmaf(d, d, srg_p); } \
        _Pragma("unroll")                                                      \
        for (int c = 0; c < 9; c++) { float d = xbuf[(j)&1][c][inner]   - f[c];   srg_m = fmaf(d, d, srg_m); } \
      }                                                                        \
    } }

#define RESET()                                                                \
  { _Pragma("unroll")                                                          \
    for (int c = 0; c < 16; c++) f[c] = 0.f;                                   \
    f[0] = f[4] = f[8] = 1.f;                                                  \
    f[12] = pq[0]; f[13] = pq[1]; f[14] = pq[2]; f[15] = pq[3]; }

#define SAVE()                                                                 \
  { _Pragma("unroll")                                                          \
    for (int c = 0; c < 16; c++) sv[c] = f[c]; }

#define RESTORE()                                                              \
  { _Pragma("unroll")                                                          \
    for (int c = 0; c < 16; c++) f[c] = sv[c]; }

  // ---- ladder: depth-1 prefetch, fully unrolled, single stream per thread ----
  LOADJ(S0, 1);
  SBAR();
  RESET();
  LOADJ(S1, 2);  COMP(S0, 1);  XCHG(1, 0);  SBAR();
  LOADJ(S0, 3);  COMP(S1, 2);  XCHG(2, 0);  SBAR();
  LOADJ(S1, 4);  COMP(S0, 3);  XCHG(3, 0);  SBAR();
  LOADJ(S0, 5);  COMP(S1, 4);  XCHG(4, 1);  RESET(); SBAR();
  LOADJ(S1, 6);  COMP(S0, 5);  XCHG(5, 0);  SBAR();
  LOADJ(S0, 7);  COMP(S1, 6);  XCHG(6, 0);  SBAR();
  LOADJ(S1, 8);  COMP(S0, 7);  XCHG(7, 0);  SBAR();
  LOADJ(S0, 9);  COMP(S1, 8);  XCHG(8, 1);  RESET(); SBAR();
  LOADJ(S1, 10); COMP(S0, 9);  XCHG(9, 0);  SBAR();
  LOADJ(S0, 11); COMP(S1, 10); XCHG(10, 0); SBAR();
  LOADJ(S1, 12); COMP(S0, 11); XCHG(11, 0); SAVE(); SBAR();
  LOADJ(S0, 13); COMP(S1, 12); XCHG(12, 0); SBAR();
  LOADJ(S1, 14); COMP(S0, 13); XCHG(13, 1); RESTORE(); SBAR();
  LOADJ(S0, 15); COMP(S1, 14); XCHG(14, 0); SBAR();
  LOADJ(S1, 16); COMP(S0, 15); XCHG(15, 0); SBAR();
  LOADJ(S0, 17); COMP(S1, 16); XCHG(16, 0); SBAR();
  LOADJ(S1, 18); COMP(S0, 17); XCHG(17, 1); RESTORE(); SBAR();
  LOADJ(S0, 19); COMP(S1, 18); XCHG(18, 0); SBAR();
  LOADJ(S1, 20); COMP(S0, 19); XCHG(19, 0); SBAR();
  LOADJ(S0, 21); COMP(S1, 20); XCHG(20, 0); SBAR();
  COMP(S0, 21); XCHG(21, 1);

#undef LOADJ
#undef COMP
#undef XCHG
#undef RESET
#undef SAVE
#undef RESTORE

  // weights: see_p/(BT*15) + see_m/(BT*45) + 0.1*(srg_p/(BT*48) + srg_m/(BT*144))
  const float W1 = 1.0f / 1966080.0f;
  const float W2 = 1.0f / 5898240.0f;
  const float W3 = 0.1f / 6291456.0f;
  const float W4 = 0.1f / 18874368.0f;
  float val = see_p * W1 + see_m * W2 + srg_p * W3 + srg_m * W4;

  #pragma unroll
  for (int o = 32; o > 0; o >>= 1) val += __shfl_down(val, o, 64);
  const int wid = tid >> 6, lane = tid & 63;
  if (lane == 0) s_wsum[wid] = val;
  __syncthreads();
  if (tid == 0) {
    float s = 0.f;
    #pragma unroll
    for (int w = 0; w < 12; w++) s += s_wsum[w];
    atomicAdd(out, s);
  }
}

extern "C" void kernel_launch(void* const* d_in, const int* in_sizes, int n_in,
                              void* d_out, int out_size, void* d_ws, size_t ws_size,
                              hipStream_t stream) {
  const float* ik   = (const float*)d_in[1];
  const float* dec  = (const float*)d_in[2];
  const float* tgt  = (const float*)d_in[3];
  const float* mean = (const float*)d_in[4];
  const float* stdv = (const float*)d_in[5];
  const float* offs = (const float*)d_in[6];
  float* out = (float*)d_out;

  hipMemsetAsync(out, 0, sizeof(float), stream);
  fk_loss_kernel<<<dim3(512), dim3(768), 0, stream>>>(ik, dec, tgt, mean, stdv, offs, out);
}